// Round 12
// baseline (161.976 us; speedup 1.0000x reference)
//
#include <hip/hip_runtime.h>
#include <hip/hip_fp16.h>

#define B_SZ  256
#define IC    1152
#define ID    8
#define OC    10
#define ROWH  160      // halves per (b,i) row of u_hat
#define CH    20       // uint4 (8-half) chunks per row

// ---------------------------------------------------------------------------
// K1: u_hat[i][b][od] = sum_k W[i][od][k] * u[b][i][k], fp16, [i][b] layout.
// grid = 2304 (block = i * 2 + od-half), 256 threads (thread = b).
// od-split x2 vs R11: halves per-thread LDS traffic (160 b128 vs 320) and
// doubles resident waves (9216 total, ~8 blocks/CU) to hide LDS+FMA latency.
// W half-slice (2.5 KB) in LDS broadcast; 10 uint4 burst store per lane.
// ---------------------------------------------------------------------------
__global__ __launch_bounds__(256) void uhat_ib_kernel(
    const float* __restrict__ u, const float* __restrict__ W,
    uint4* __restrict__ uhat)
{
    const int bx   = blockIdx.x;
    const int i    = bx >> 1;
    const int half = bx & 1;
    const int b    = threadIdx.x;

    __shared__ float4 Wl[ROWH];   // 80 od x 8 k = 640 f32 = 160 float4 = 2.5 KB

    const float4* wsrc = (const float4*)(W + (size_t)i * ROWH * ID) + half * ROWH;
    for (int idx = b; idx < ROWH; idx += 256) Wl[idx] = wsrc[idx];

    const float4* up = (const float4*)(u + ((size_t)b * IC + i) * ID);
    float4 u0 = up[0], u1 = up[1];
    __syncthreads();

    uint4 ro[CH / 2];
    #pragma unroll
    for (int c4 = 0; c4 < CH / 2; ++c4) {
        float o[8];
        #pragma unroll
        for (int j = 0; j < 8; ++j) {
            float4 wa = Wl[(c4 * 8 + j) * 2];
            float4 wb = Wl[(c4 * 8 + j) * 2 + 1];
            o[j] = wa.x * u0.x + wa.y * u0.y + wa.z * u0.z + wa.w * u0.w
                 + wb.x * u1.x + wb.y * u1.y + wb.z * u1.z + wb.w * u1.w;
        }
        union { __half2 h2[4]; uint4 q; } pk;
        pk.h2[0] = __floats2half2_rn(o[0], o[1]);
        pk.h2[1] = __floats2half2_rn(o[2], o[3]);
        pk.h2[2] = __floats2half2_rn(o[4], o[5]);
        pk.h2[3] = __floats2half2_rn(o[6], o[7]);
        ro[c4] = pk.q;
    }

    uint4* dst = uhat + ((size_t)i * B_SZ + b) * CH + half * (CH / 2);
    #pragma unroll
    for (int c4 = 0; c4 < CH / 2; ++c4) dst[c4] = ro[c4];
}

// ---------------------------------------------------------------------------
// K2: all 3 routing passes. One block per b, 1024 threads = 16 waves.
// Lane = ii*16 + os; lane owns the full 32B u_hat row for its (i,o).
// Changes vs R11 (both pure-ILP, geometry/layout identical):
//  - depth-3 pipeline with NAMED regs A/B/C under #pragma unroll 3
//    (rotation by static copies -> register renaming, no scratch; rule #20)
//  - agreement dot as explicit 2-level tree (8x2-term fma -> 4 -> 2 -> 1):
//    dependent-chain latency ~64 -> ~20 cyc
// u_hat layout [i][b]: row (i,b) at ((i*256)+b)*320 bytes.
// ---------------------------------------------------------------------------
__global__ __launch_bounds__(1024, 4) void routing3_kernel(
    const uint4* __restrict__ uhat, float* __restrict__ out)
{
    const int b  = blockIdx.x;
    const int t  = threadIdx.x;
    const int wv = t >> 6;
    const int ln = t & 63;
    const int ii = ln >> 4;
    const int os = ln & 15;
    const bool act = (os < OC);
    const int o  = act ? os : (OC - 1);

    __shared__ float sred[16][164];   // +4 pad
    __shared__ float vl[ROWH];

    // step it: i = wv*72 + it*4 + ii
    const char* base = (const char*)uhat
                     + ((size_t)(wv * 72 + ii) * B_SZ + b) * 320 + o * 32;
    const size_t STEP = (size_t)4 * B_SZ * 320;   // advance 4 i per step

    float v[16];
    #pragma unroll
    for (int j = 0; j < 16; ++j) v[j] = 0.f;

    for (int p = 0; p < 3; ++p) {
        float s[16];
        #pragma unroll
        for (int j = 0; j < 16; ++j) s[j] = 0.f;

        uint4 A0 = *(const uint4*)(base);
        uint4 A1 = *(const uint4*)(base + 16);
        uint4 B0 = *(const uint4*)(base + STEP);
        uint4 B1 = *(const uint4*)(base + STEP + 16);
        uint4 C0 = *(const uint4*)(base + 2 * STEP);
        uint4 C1 = *(const uint4*)(base + 2 * STEP + 16);

        #pragma unroll 3
        for (int it = 0; it < 18; ++it) {
            uint4 N0 = C0, N1 = C1;
            if (it + 3 < 18) {
                const char* np = base + (size_t)(it + 3) * STEP;
                N0 = *(const uint4*)np;
                N1 = *(const uint4*)(np + 16);
            }

            float r[16];
            const __half2* hp0 = (const __half2*)&A0;
            const __half2* hp1 = (const __half2*)&A1;
            #pragma unroll
            for (int q = 0; q < 4; ++q) {
                float2 f = __half22float2(hp0[q]);
                float2 g = __half22float2(hp1[q]);
                r[2 * q]     = f.x; r[2 * q + 1] = f.y;
                r[8 + 2 * q] = g.x; r[9 + 2 * q] = g.y;
            }

            if (p == 0) {
                #pragma unroll
                for (int j = 0; j < 16; ++j) s[j] += r[j];   // c uniform; 0.1 later
            } else {
                // 2-level tree dot: 8 independent 2-term partials -> 4 -> 2 -> 1
                float t0 = fmaf(r[1],  v[1],  r[0]  * v[0]);
                float t1 = fmaf(r[3],  v[3],  r[2]  * v[2]);
                float t2 = fmaf(r[5],  v[5],  r[4]  * v[4]);
                float t3 = fmaf(r[7],  v[7],  r[6]  * v[6]);
                float t4 = fmaf(r[9],  v[9],  r[8]  * v[8]);
                float t5 = fmaf(r[11], v[11], r[10] * v[10]);
                float t6 = fmaf(r[13], v[13], r[12] * v[12]);
                float t7 = fmaf(r[15], v[15], r[14] * v[14]);
                float u0 = t0 + t1, u1 = t2 + t3, u2 = t4 + t5, u3 = t6 + t7;
                float a = (u0 + u1) + (u2 + u3);

                float e = act ? __expf(a) : 0.f;
                float Z = e;
                Z += __shfl_xor(Z, 1);
                Z += __shfl_xor(Z, 2);
                Z += __shfl_xor(Z, 4);
                Z += __shfl_xor(Z, 8);
                float cf = __fdividef(e, Z);

                #pragma unroll
                for (int j = 0; j < 16; ++j) s[j] += cf * r[j];
            }

            A0 = B0; A1 = B1; B0 = C0; B1 = C1; C0 = N0; C1 = N1;
        }

        // reduce over the 4 ii (lanes xor 16, 32 share the same os)
        #pragma unroll
        for (int j = 0; j < 16; ++j) {
            s[j] += __shfl_xor(s[j], 16);
            s[j] += __shfl_xor(s[j], 32);
        }
        if (ln < 16 && act) {   // ii==0, os<10: wave-total for o=os
            float4* dst = (float4*)&sred[wv][os * 16];
            dst[0] = make_float4(s[0],  s[1],  s[2],  s[3]);
            dst[1] = make_float4(s[4],  s[5],  s[6],  s[7]);
            dst[2] = make_float4(s[8],  s[9],  s[10], s[11]);
            dst[3] = make_float4(s[12], s[13], s[14], s[15]);
        }
        __syncthreads();

        if (t < ROWH) {
            float S = 0.f;
            #pragma unroll
            for (int w2 = 0; w2 < 16; ++w2) S += sred[w2][t];
            if (p == 0) S *= 0.1f;
            float n2 = S * S;
            n2 += __shfl_xor(n2, 1);
            n2 += __shfl_xor(n2, 2);
            n2 += __shfl_xor(n2, 4);
            n2 += __shfl_xor(n2, 8);
            float sc = (n2 / (1.0f + n2)) * rsqrtf(n2 + 1e-8f);
            vl[t] = S * sc;
        }
        __syncthreads();

        if (p < 2) {   // v <- v0 (p0) ; v <- v0+v1 (p1)
            const float4* vp = (const float4*)&vl[o * 16];
            float4 q0 = vp[0], q1 = vp[1], q2 = vp[2], q3 = vp[3];
            if (p == 0) {
                v[0]=q0.x; v[1]=q0.y; v[2]=q0.z; v[3]=q0.w;
                v[4]=q1.x; v[5]=q1.y; v[6]=q1.z; v[7]=q1.w;
                v[8]=q2.x; v[9]=q2.y; v[10]=q2.z; v[11]=q2.w;
                v[12]=q3.x; v[13]=q3.y; v[14]=q3.z; v[15]=q3.w;
            } else {
                v[0]+=q0.x; v[1]+=q0.y; v[2]+=q0.z; v[3]+=q0.w;
                v[4]+=q1.x; v[5]+=q1.y; v[6]+=q1.z; v[7]+=q1.w;
                v[8]+=q2.x; v[9]+=q2.y; v[10]+=q2.z; v[11]+=q2.w;
                v[12]+=q3.x; v[13]+=q3.y; v[14]+=q3.z; v[15]+=q3.w;
            }
            __syncthreads();   // protect sred/vl before next pass rewrites them
        }
    }

    if (t < 2 * CH) {
        ((float4*)out)[(size_t)b * 2 * CH + t] = ((const float4*)vl)[t];
    }
}

// ---------------------------------------------------------------------------
extern "C" void kernel_launch(void* const* d_in, const int* in_sizes, int n_in,
                              void* d_out, int out_size, void* d_ws, size_t ws_size,
                              hipStream_t stream)
{
    const float* u = (const float*)d_in[0];
    const float* W = (const float*)d_in[1];

    uint4* uhat = (uint4*)d_ws;   // 1152*256*320 B = 94.4 MB, [i][b] layout

    uhat_ib_kernel<<<IC * 2, 256, 0, stream>>>(u, W, uhat);
    routing3_kernel<<<B_SZ, 1024, 0, stream>>>(uhat, (float*)d_out);
}